// Round 11
// baseline (112.810 us; speedup 1.0000x reference)
//
#include <hip/hip_runtime.h>
#include <hip/hip_bf16.h>

// Problem constants
static constexpr int Bn = 8, Cn = 128, Hn = 64, Wn = 64, Con = 128;
static constexpr int KKn = 9, DGn = 2, Cgn = 64;
static constexpr int HOn = 64, WOn = 64;
static constexpr int PITCH = 72;     // bf16 row pitch for s_val rows
static constexpr int OMP3 = 66;      // s_om row pitch (shorts), 64 pos + pad

typedef short short8 __attribute__((ext_vector_type(8)));
typedef float f32x4  __attribute__((ext_vector_type(4)));

__device__ __forceinline__ unsigned short f2bf(float f) {
    unsigned u = __float_as_uint(f);
    u += 0x7fff + ((u >> 16) & 1);          // round-to-nearest-even
    return (unsigned short)(u >> 16);
}
__device__ __forceinline__ float bf2f(unsigned short h) {
    return __uint_as_float(((unsigned)h) << 16);
}

// ---------------------------------------------------------------------------
// Kernel P (R18): WEIGHTS-ONLY prep (x transpose eliminated; proven win).
// Blocks [0,576):   main weight -> MFMA B-frag order wt2[gk][ks][tile][lane][8].
// Blocks [576,720): offset weight -> owf[g][ks=tap*2+ch][nt][lane][8].
// ---------------------------------------------------------------------------
__global__ __launch_bounds__(256) void prep(const float* __restrict__ w,
                                            const float* __restrict__ ow,
                                            unsigned short* __restrict__ wt2,
                                            unsigned short* __restrict__ owf) {
    const int blk = blockIdx.x;
    const int t = threadIdx.x;
    if (blk < 576) {
        int e    = blk * 256 + t;                // [0,147456)
        int j    = e & 7;
        int lane = (e >> 3) & 63;
        int tile = (e >> 9) & 7;
        int ks   = (e >> 12) & 1;
        int gk   = e >> 13;                      // 0..17
        int g = gk / 9, k = gk - g * 9;
        int oc = tile * 16 + (lane & 15);
        int c  = ks * 32 + (lane >> 4) * 8 + j;
        wt2[e] = f2bf(w[((size_t)oc * Cn + g * Cgn + c) * KKn + k]);
    } else {
        int e = (blk - 576) * 256 + t;           // [0,36864)
        int g  = e / 18432;
        int r  = e - g * 18432;
        int ks = r >> 10;
        int r2 = r & 1023;
        int nt = r2 >> 9;
        int lane = (r2 >> 3) & 63;
        int j  = r2 & 7;
        int tap = ks >> 1, chalf = ks & 1;
        int oc_l = nt * 16 + (lane & 15);
        int c = chalf * 32 + (lane >> 4) * 8 + j;
        float v = 0.f;
        if (oc_l < 27)
            v = ow[((size_t)(g * 27 + oc_l) * Cgn + c) * KKn + tap];
        owf[e] = f2bf(v);
    }
}

// ---------------------------------------------------------------------------
// Kernel 2 (R19): R18 structure + PRODUCER INSTRUCTION DIET.
// R18 counters: VALUBusy 45% with 8/16 waves producing -> producer waves are
// ~90-100% VALU-issue-bound; that's the wall. Cuts (math order preserved,
// output bit-identical):
//   1. P1 pre-encodes corner address codes e=(yc<<10)|(xc<<4)|(xc&15) in
//      s_pk2 (int2): producer addr math ~7 -> ~4 ops/corner.
//   2. Bilinear as u32-pair float2 ops (compiler can emit v_pk_fma_f32).
//   3. bf16 pack via v_cvt_pk_bf16_f32 (RNE, bit-identical): 24 -> 4 ops.
// LDS: 114688 (s_xw) + 18432 (s_val dbuf, s_om aliased) + 18432 (s_cw)
//      + 9216 (s_pk2) = 160768 B <= 163840 -> 1 block/CU, 16 waves.
// ---------------------------------------------------------------------------
__global__ __launch_bounds__(1024, 4) void dcn_fused(const float* __restrict__ x,
                                                     const unsigned short* __restrict__ owf,
                                                     const float* __restrict__ ob,
                                                     const unsigned short* __restrict__ wt2,
                                                     float* __restrict__ out) {
    __shared__ __align__(16) unsigned short s_xw[7 * 64 * 16 * 8];   // 114688 B window
    __shared__ __align__(16) unsigned short s_val[2][64 * PITCH];    // 18432 B dbuf
    __shared__ float4 s_cw[18][64];                                  // 18432 B
    __shared__ int2   s_pk2[18][64];                                 // 9216 B

    unsigned short* s_om = &s_val[0][0];     // alias: s_om (7128 B) lives pre-P2

    const int t  = threadIdx.x;              // [0,1024)
    const int id = blockIdx.x;               // [0,512)
    const int b  = id & 7;                   // XCD-aware: batch b -> XCD b
    const int ho = id >> 3;                  // full output row

    const int lane = t & 63;
    const int wv   = t >> 6;                 // wave id 0..15
    const int lr   = lane & 15;              // MFMA row/col part
    const int lk   = (lane >> 4) * 8;        // MFMA k offset (shorts)
    const int q    = lane >> 4;              // D row quad

    const int lo = max(0, ho - 3);
    const int hi = min(Hn - 1, ho + 3);
    const int nrows = hi - lo + 1;           // <= 7

    const float* xb4 = x + (size_t)b * Cn * Hn * Wn;   // NCHW batch base
    const short8 zz = {0, 0, 0, 0, 0, 0, 0, 0};

    // ---- S: stage x window rows [lo,hi] into LDS, transposing on the fly ----
    for (int u = t; u < nrows * 1024; u += 1024) {
        int xx = u & 63;
        int kk = (u >> 6) & 15;
        int rs = u >> 10;
        int y  = lo + rs;
        short8 v;
#pragma unroll
        for (int j = 0; j < 8; ++j) {
            float f = xb4[(((size_t)(kk * 8 + j) * Hn) + y) * Wn + xx];
            v[j] = (short)f2bf(f);
        }
        *(short8*)&s_xw[(((rs * 64 + xx) * 16) + (kk ^ (xx & 15))) * 8] = v;
    }
    __syncthreads();

    // ---- P0: offset-conv GEMM on ALL 16 waves, A from LDS window ----
    {
        const int cg = wv >> 3;              // conv/deform group
        const int rh4 = (wv >> 1) & 3;       // row quarter (pos base rh4*16)
        const int nh = wv & 1;               // oc 16-block
        const int oc_l = nh * 16 + lr;
        float bias = (oc_l < 27) ? ob[cg * 27 + oc_l] : 0.f;
        f32x4 oacc = (f32x4){bias, bias, bias, bias};

        const unsigned short* wf = owf + (size_t)cg * 18432;

        for (int tap = 0; tap < 9; ++tap) {
            int ky = tap / 3, kx = tap - ky * 3;
            int y = ho - 2 + 2 * ky;
            if (y < 0 || y >= Hn) continue;  // wave-uniform skip (zero pad)
            int slot = y - lo;               // y in [lo,hi] guaranteed
#pragma unroll
            for (int ch = 0; ch < 2; ++ch) {
                int kssl = tap * 2 + ch;
                short8 bv = *(const short8*)&wf[(size_t)kssl * 1024 + nh * 512 + lane * 8];
                int wo = rh4 * 16 + lr;
                int xc = wo - 2 + 2 * kx;
                bool vx = (xc >= 0) & (xc < Wn);
                int xcc = min(max(xc, 0), Wn - 1);
                int kk  = (cg * 8 + ch * 4 + (lane >> 4)) ^ (xcc & 15);
                short8 av = *(const short8*)&s_xw[(((slot * 64 + xcc) * 16) + kk) * 8];
                av = vx ? av : zz;
                oacc = __builtin_amdgcn_mfma_f32_16x16x32_bf16(av, bv, oacc, 0, 0, 0);
            }
        }
        if (oc_l < 27) {
            int c54 = cg * 27 + oc_l;
#pragma unroll
            for (int r = 0; r < 4; ++r)
                s_om[c54 * OMP3 + rh4 * 16 + q * 4 + r] = f2bf(oacc[r]);
        }
    }
    __syncthreads();

    // ---- P1: sampling params; corner addresses pre-encoded ----
    for (int e = t; e < 18 * 64; e += 1024) {
        int pos = e & 63;
        int wo  = pos;
        int gk  = e >> 6;
        int g  = gk / 9, k = gk - g * 9;
        int ky = k / 3,  kx = k - ky * 3;
        float offy = bf2f(s_om[(g * 18 + k * 2 + 0) * OMP3 + pos]);
        float offx = bf2f(s_om[(g * 18 + k * 2 + 1) * OMP3 + pos]);
        float mk   = bf2f(s_om[(36 + g * 9 + k) * OMP3 + pos]);
        mk = 2.0f / (1.0f + __expf(-mk));

        float py = offy + (float)(ky * 2 + ho - 2);
        float px = offx + (float)(kx * 2 + wo - 2);
        float fy = floorf(py), fx = floorf(px);
        int   y0 = (int)fy,    x0 = (int)fx;
        float wy = py - fy,    wx = px - fx;

        bool vy0 = (y0 >= 0) & (y0 < Hn);
        bool vy1 = (y0 + 1 >= 0) & (y0 + 1 < Hn);
        bool vx0 = (x0 >= 0) & (x0 < Wn);
        bool vx1 = (x0 + 1 >= 0) & (x0 + 1 < Wn);
        float4 cw;
        cw.x = (vy0 & vx0) ? (1.f - wy) * (1.f - wx) * mk : 0.f;
        cw.y = (vy0 & vx1) ? (1.f - wy) * wx * mk : 0.f;
        cw.z = (vy1 & vx0) ? wy * (1.f - wx) * mk : 0.f;
        cw.w = (vy1 & vx1) ? wy * wx * mk : 0.f;

        int y0c = min(max(y0, 0), Hn - 1);
        int y1c = min(max(y0 + 1, 0), Hn - 1);
        int x0c = min(max(x0, 0), Wn - 1);
        int x1c = min(max(x0 + 1, 0), Wn - 1);

        // address codes: e = (yc<<10) | (xc<<4) | (xc&15)  (16 bits)
        unsigned e00 = ((unsigned)y0c << 10) | ((unsigned)x0c << 4) | (unsigned)(x0c & 15);
        unsigned e01 = ((unsigned)y0c << 10) | ((unsigned)x1c << 4) | (unsigned)(x1c & 15);
        unsigned e10 = ((unsigned)y1c << 10) | ((unsigned)x0c << 4) | (unsigned)(x0c & 15);
        unsigned e11 = ((unsigned)y1c << 10) | ((unsigned)x1c << 4) | (unsigned)(x1c & 15);
        s_cw[gk][pos] = cw;
        s_pk2[gk][pos] = make_int2((int)(e00 | (e01 << 16)), (int)(e10 | (e11 << 16)));
    }
    __syncthreads();   // also fences s_om -> s_val reuse

    // ---- P2: producer/consumer gk loop (R18 structure), one barrier per gk ----
    auto gather_tile = [&](int gkj) {
        const int pos = t >> 3;              // 0..63 (t < 512)
        const int c8  = t & 7;               // 8-ch chunk id
        const int g   = (gkj >= 9) ? 1 : 0;
        const int kg  = g * 8 + c8;
        float4 cw = s_cw[gkj][pos];
        int2  pk  = s_pk2[gkj][pos];
        unsigned px0 = (unsigned)pk.x, px1 = (unsigned)pk.y;
        unsigned e00 = px0 & 0xffffu, e01 = px0 >> 16;
        unsigned e10 = px1 & 0xffffu, e11 = px1 >> 16;
        int y0c = (int)(e00 >> 10), y1c = (int)(e10 >> 10);

        short8 a00, a01, a10, a11;
        bool ok = (y0c >= lo) & (y1c <= hi);
        if (__all(ok)) {
            const int base = lo << 6;        // subtract from (e>>4) = yc*64+xc
            {
                int i00 = (((int)(e00 >> 4) - base) << 4) + (kg ^ (int)(e00 & 15));
                int i01 = (((int)(e01 >> 4) - base) << 4) + (kg ^ (int)(e01 & 15));
                int i10 = (((int)(e10 >> 4) - base) << 4) + (kg ^ (int)(e10 & 15));
                int i11 = (((int)(e11 >> 4) - base) << 4) + (kg ^ (int)(e11 & 15));
                a00 = *(const short8*)&s_xw[i00 << 3];
                a01 = *(const short8*)&s_xw[i01 << 3];
                a10 = *(const short8*)&s_xw[i10 << 3];
                a11 = *(const short8*)&s_xw[i11 << 3];
            }
        } else {
            // rare fallback (offsets beyond window): read NCHW x directly.
            int x0c = (int)((e00 >> 4) & 63), x1c = (int)((e01 >> 4) & 63);
            const float* xc0 = xb4 + (size_t)(g * Cgn + c8 * 8) * Hn * Wn;
#pragma unroll
            for (int j = 0; j < 8; ++j) {
                const float* xj = xc0 + (size_t)j * Hn * Wn;
                a00[j] = (short)f2bf(xj[(size_t)y0c * Wn + x0c]);
                a01[j] = (short)f2bf(xj[(size_t)y0c * Wn + x1c]);
                a10[j] = (short)f2bf(xj[(size_t)y1c * Wn + x0c]);
                a11[j] = (short)f2bf(xj[(size_t)y1c * Wn + x1c]);
            }
        }

        // bilinear on u32 channel-pairs (lo/hi bf16), pack via cvt_pk (RNE).
        const unsigned* u00 = (const unsigned*)&a00;
        const unsigned* u01 = (const unsigned*)&a01;
        const unsigned* u10 = (const unsigned*)&a10;
        const unsigned* u11 = (const unsigned*)&a11;
        short8 h0;
        unsigned* h32 = (unsigned*)&h0;
#pragma unroll
        for (int p = 0; p < 4; ++p) {
            float l0 = __uint_as_float(u00[p] << 16), h0f = __uint_as_float(u00[p] & 0xffff0000u);
            float l1 = __uint_as_float(u01[p] << 16), h1f = __uint_as_float(u01[p] & 0xffff0000u);
            float l2 = __uint_as_float(u10[p] << 16), h2f = __uint_as_float(u10[p] & 0xffff0000u);
            float l3 = __uint_as_float(u11[p] << 16), h3f = __uint_as_float(u11[p] & 0xffff0000u);
            float vlo = cw.x * l0 + cw.y * l1 + cw.z * l2 + cw.w * l3;
            float vhi = cw.x * h0f + cw.y * h1f + cw.z * h2f + cw.w * h3f;
            unsigned pkd;
            asm("v_cvt_pk_bf16_f32 %0, %1, %2" : "=v"(pkd) : "v"(vlo), "v"(vhi));
            h32[p] = pkd;
        }
        *(short8*)&s_val[gkj & 1][(t >> 3) * PITCH + c8 * 8] = h0;
    };

    f32x4 acc[2][2];                         // [i = mt in pair][j = oc-16 in pair]
#pragma unroll
    for (int i = 0; i < 2; ++i)
#pragma unroll
        for (int j = 0; j < 2; ++j) acc[i][j] = (f32x4){0.f, 0.f, 0.f, 0.f};

    if (wv < 8) gather_tile(0);              // prologue fill buf0

    const int cid = wv - 8;                  // consumer id 0..7 (wv >= 8)
    const int rh2 = cid >> 2;                // mt pair: rows (rh2*2+i)*16
    const int nt2 = cid & 3;                 // oc-32: tiles nt2*2 + j

    for (int gk = 0; gk < 18; ++gk) {
        __syncthreads();                     // s_val[gk&1] ready for consumers
        if (wv < 8) {
            if (gk < 17) gather_tile(gk + 1);   // fill other buffer concurrently
        } else {
            const unsigned short* wf = wt2 + (size_t)gk * 8192;
#pragma unroll
            for (int ks = 0; ks < 2; ++ks) {
                short8 af[2];
#pragma unroll
                for (int i = 0; i < 2; ++i)
                    af[i] = *(const short8*)&s_val[gk & 1][((rh2 * 2 + i) * 16 + lr) * PITCH + ks * 32 + lk];
#pragma unroll
                for (int i = 0; i < 2; ++i)
#pragma unroll
                    for (int j = 0; j < 2; ++j) {
                        short8 bfr = *(const short8*)&wf[(size_t)(ks * 8 + nt2 * 2 + j) * 512 + lane * 8];
                        acc[i][j] = __builtin_amdgcn_mfma_f32_16x16x32_bf16(af[i], bfr, acc[i][j], 0, 0, 0);
                    }
            }
        }
    }

    // ---- epilogue (consumers): oc = (nt2*2+j)*16 + lr; rows (rh2*2+i)*16 + q*4 ----
    if (wv >= 8) {
#pragma unroll
        for (int i = 0; i < 2; ++i)
#pragma unroll
            for (int j = 0; j < 2; ++j) {
                int oc = (nt2 * 2 + j) * 16 + lr;
                int p0 = (rh2 * 2 + i) * 16 + q * 4;
                float4 v = {acc[i][j][0], acc[i][j][1], acc[i][j][2], acc[i][j][3]};
                *(float4*)&out[(((size_t)b * Con + oc) * HOn + ho) * WOn + p0] = v;
            }
    }
}

// ---------------------------------------------------------------------------
extern "C" void kernel_launch(void* const* d_in, const int* in_sizes, int n_in,
                              void* d_out, int out_size, void* d_ws, size_t ws_size,
                              hipStream_t stream) {
    const float* x  = (const float*)d_in[0];   // [8,128,64,64]
    const float* ow = (const float*)d_in[1];   // [54,64,3,3]
    const float* ob = (const float*)d_in[2];   // [54]
    const float* w  = (const float*)d_in[3];   // [128,128,3,3]
    float* out = (float*)d_out;                // [8,128,64,64]

    // ws: wt2 294,912 | owf 73,728
    unsigned short* wt2 = (unsigned short*)d_ws;
    unsigned short* owf = (unsigned short*)((char*)d_ws + 294912);

    hipLaunchKernelGGL(prep, dim3(720), dim3(256), 0, stream,
                       w, ow, wt2, owf);
    hipLaunchKernelGGL(dcn_fused, dim3(512), dim3(1024), 0, stream,
                       x, owf, ob, wt2, out);
}